// Round 1
// baseline (1609.958 us; speedup 1.0000x reference)
//
#include <hip/hip_runtime.h>
#include <cstdio>
#include <cstdint>

#define NN  8
#define CCH 256
#define HWP 25200
#define SS  2520
#define KCL 315
#define KNN 10

__device__ __forceinline__ unsigned fmap(float f) {
  unsigned u = __float_as_uint(f);
  return (u & 0x80000000u) ? ~u : (u | 0x80000000u);
}
__device__ __forceinline__ float funmap(unsigned u) {
  unsigned b = (u & 0x80000000u) ? (u & 0x7fffffffu) : ~u;
  return __uint_as_float(b);
}

// ---------------- K0: score net (fp32 GEMM + relu + dot + sigmoid) ----------
__global__ __launch_bounds__(256) void k_score(
    const float* __restrict__ x, const float* __restrict__ w1,
    const float* __restrict__ b1, const float* __restrict__ w2,
    const float* __restrict__ b2, const float* __restrict__ pri,
    float* __restrict__ scores)
{
  __shared__ float Wl[32 * 260];   // [c'][d], padded stride 260
  __shared__ float Xl[32 * 64];    // [c'][p]
  const int n = blockIdx.y;
  const int p0 = blockIdx.x * 64;
  const int tid = threadIdx.x;
  const int dgrp = tid >> 4;   // d base = 16*dgrp
  const int pgrp = tid & 15;   // p base = 4*pgrp
  float acc[16][4];
#pragma unroll
  for (int i = 0; i < 16; ++i)
#pragma unroll
    for (int j = 0; j < 4; ++j) acc[i][j] = 0.f;

  for (int c0 = 0; c0 < CCH; c0 += 32) {
    for (int l = tid; l < 2048; l += 256) {
      int d = l >> 3, q = l & 7;
      float4 v = *(const float4*)&w1[d * CCH + c0 + 4 * q];
      Wl[(4 * q + 0) * 260 + d] = v.x;
      Wl[(4 * q + 1) * 260 + d] = v.y;
      Wl[(4 * q + 2) * 260 + d] = v.z;
      Wl[(4 * q + 3) * 260 + d] = v.w;
    }
    for (int l = tid; l < 512; l += 256) {
      int cc = l >> 4, q = l & 15;
      int gp = p0 + 4 * q; if (gp > HWP - 4) gp = HWP - 4;
      float4 v = *(const float4*)&x[(size_t)(n * CCH + c0 + cc) * HWP + gp];
      *(float4*)&Xl[cc * 64 + 4 * q] = v;
    }
    __syncthreads();
#pragma unroll 4
    for (int kk = 0; kk < 32; ++kk) {
      const float4 xv = *(const float4*)&Xl[kk * 64 + pgrp * 4];
      const float* wp = &Wl[kk * 260 + dgrp * 16];
#pragma unroll
      for (int i = 0; i < 16; i += 4) {
        const float4 a = *(const float4*)&wp[i];
        acc[i+0][0] += a.x*xv.x; acc[i+0][1] += a.x*xv.y; acc[i+0][2] += a.x*xv.z; acc[i+0][3] += a.x*xv.w;
        acc[i+1][0] += a.y*xv.x; acc[i+1][1] += a.y*xv.y; acc[i+1][2] += a.y*xv.z; acc[i+1][3] += a.y*xv.w;
        acc[i+2][0] += a.z*xv.x; acc[i+2][1] += a.z*xv.y; acc[i+2][2] += a.z*xv.z; acc[i+2][3] += a.z*xv.w;
        acc[i+3][0] += a.w*xv.x; acc[i+3][1] += a.w*xv.y; acc[i+3][2] += a.w*xv.z; acc[i+3][3] += a.w*xv.w;
      }
    }
    __syncthreads();
  }
  float part[4] = {0.f, 0.f, 0.f, 0.f};
#pragma unroll
  for (int i = 0; i < 16; ++i) {
    int d = dgrp * 16 + i;
    float bb = b1[d], wv = w2[d];
#pragma unroll
    for (int j = 0; j < 4; ++j) {
      float h = acc[i][j] + bb; h = h > 0.f ? h : 0.f;
      part[j] += h * wv;
    }
  }
  float* red = Xl;  // 64*16 floats
  for (int j = 0; j < 4; ++j) red[(pgrp * 4 + j) * 16 + dgrp] = part[j];
  __syncthreads();
  if (tid < 64) {
    float s = b2[0];
#pragma unroll
    for (int g = 0; g < 16; ++g) s += red[tid * 16 + g];
    float sc = 1.f / (1.f + expf(-s));
    int p = p0 + tid;
    if (p < HWP) scores[n * HWP + p] = sc * pri[n * HWP + p];
  }
}

// ---------------- shared bitonic (4096 u64 desc, 1024 thr) ------------------
__device__ __forceinline__ void bitonic4096_desc(unsigned long long* keys, int tid) {
  for (int k = 2; k <= 4096; k <<= 1) {
    for (int j = k >> 1; j > 0; j >>= 1) {
      for (int i = tid; i < 4096; i += 1024) {
        int ixj = i ^ j;
        if (ixj > i) {
          unsigned long long a = keys[i], b = keys[ixj];
          bool up = ((i & k) == 0);
          if ((a < b) == up) { keys[i] = b; keys[ixj] = a; }
        }
      }
      __syncthreads();
    }
  }
}

// ---------------- K1: exact top-S sample (radix select + sort) --------------
__global__ __launch_bounds__(1024) void k_topk_sample(
    const float* __restrict__ scores, int* __restrict__ topk_idx, float* __restrict__ conf)
{
  __shared__ unsigned hist[256];
  __shared__ unsigned long long keys[4096];
  __shared__ unsigned sh_rank, sh_chosen;
  __shared__ int sh_cnt;
  const int n = blockIdx.x;
  const int tid = threadIdx.x;
  if (tid == 0) sh_rank = SS;
  __syncthreads();
  unsigned prefix = 0, pmask = 0;
  for (int shift = 24; shift >= 0; shift -= 8) {
    for (int b = tid; b < 256; b += 1024) hist[b] = 0;
    __syncthreads();
    for (int e = tid; e < HWP; e += 1024) {
      unsigned u = fmap(scores[n * HWP + e]);
      if ((u & pmask) == prefix) atomicAdd(&hist[(u >> shift) & 255u], 1u);
    }
    __syncthreads();
    if (tid == 0) {
      unsigned r = sh_rank, chosen = 0;
      for (int b = 255; b >= 0; --b) {
        unsigned cb = hist[b];
        if (cb < r) r -= cb; else { chosen = (unsigned)b; break; }
      }
      sh_rank = r; sh_chosen = chosen;
    }
    __syncthreads();
    prefix |= sh_chosen << shift;
    pmask  |= 0xFFu << shift;
    __syncthreads();
  }
  const unsigned uT = prefix;
  if (tid == 0) sh_cnt = 0;
  for (int i = tid; i < 4096; i += 1024) keys[i] = 0ULL;
  __syncthreads();
  for (int e = tid; e < HWP; e += 1024) {
    unsigned u = fmap(scores[n * HWP + e]);
    if (u >= uT) {
      int s = atomicAdd(&sh_cnt, 1);
      if (s < 4096) keys[s] = ((unsigned long long)u << 32) | (unsigned)(~(unsigned)e);
    }
  }
  __syncthreads();
  bitonic4096_desc(keys, tid);
  for (int t = tid; t < SS; t += 1024) {
    unsigned long long kv = keys[t];
    topk_idx[n * SS + t] = (int)(~(unsigned)kv);
    conf[n * SS + t] = funmap((unsigned)(kv >> 32));
  }
}

// ---------------- reductions ------------------------------------------------
__device__ __forceinline__ float block_sum256(float v, float* scratch) {
#pragma unroll
  for (int o = 32; o > 0; o >>= 1) v += __shfl_down(v, o);
  int wid = threadIdx.x >> 6, lane = threadIdx.x & 63;
  if (lane == 0) scratch[wid] = v;
  __syncthreads();
  float r = scratch[0] + scratch[1] + scratch[2] + scratch[3];
  __syncthreads();
  return r;
}

// ---------------- K2: gather + layernorm + conf + sq ------------------------
__global__ __launch_bounds__(256) void k_gather_ln(
    const float* __restrict__ x, const int* __restrict__ topk_idx,
    const float* __restrict__ conf, float* __restrict__ tokens, float* __restrict__ sq)
{
  __shared__ float scratch[4];
  const int t = blockIdx.x, n = blockIdx.y, c = threadIdx.x;
  const int p = topk_idx[n * SS + t];
  float v = x[(size_t)(n * CCH + c) * HWP + p];
  float mu = block_sum256(v, scratch) * (1.f / CCH);
  float d = v - mu;
  float var = block_sum256(d * d, scratch) * (1.f / CCH);
  float inv = 1.f / sqrtf(var + 1e-5f);
  float tok = d * inv * conf[n * SS + t];
  tokens[(size_t)(n * SS + t) * CCH + c] = tok;
  float s2 = block_sum256(tok * tok, scratch);
  if (c == 0) sq[n * SS + t] = s2;
}

// ---------------- K3: gram GEMM -> d2, global max ---------------------------
__global__ __launch_bounds__(256) void k_gram(
    const float* __restrict__ tokens, const float* __restrict__ sq,
    float* __restrict__ d2, int* __restrict__ d2max)
{
  __shared__ float Al[64 * 68], Bl[64 * 68];  // [k'][row], padded 68
  __shared__ float redm[256];
  const int n = blockIdx.z, i0 = blockIdx.y * 64, j0 = blockIdx.x * 64;
  const int tid = threadIdx.x;
  const int ti = tid & 15, tj = tid >> 4;
  float acc[4][4];
#pragma unroll
  for (int a = 0; a < 4; ++a)
#pragma unroll
    for (int b = 0; b < 4; ++b) acc[a][b] = 0.f;

  for (int k0 = 0; k0 < CCH; k0 += 64) {
    for (int l = tid; l < 1024; l += 256) {
      int r = l >> 4, q = l & 15;
      int ra = i0 + r; if (ra >= SS) ra = SS - 1;
      float4 va = *(const float4*)&tokens[(size_t)(n * SS + ra) * CCH + k0 + 4 * q];
      Al[(4 * q + 0) * 68 + r] = va.x; Al[(4 * q + 1) * 68 + r] = va.y;
      Al[(4 * q + 2) * 68 + r] = va.z; Al[(4 * q + 3) * 68 + r] = va.w;
      int rb = j0 + r; if (rb >= SS) rb = SS - 1;
      float4 vb = *(const float4*)&tokens[(size_t)(n * SS + rb) * CCH + k0 + 4 * q];
      Bl[(4 * q + 0) * 68 + r] = vb.x; Bl[(4 * q + 1) * 68 + r] = vb.y;
      Bl[(4 * q + 2) * 68 + r] = vb.z; Bl[(4 * q + 3) * 68 + r] = vb.w;
    }
    __syncthreads();
#pragma unroll 8
    for (int kk = 0; kk < 64; ++kk) {
      const float4 a = *(const float4*)&Al[kk * 68 + 4 * ti];
      const float4 b = *(const float4*)&Bl[kk * 68 + 4 * tj];
      acc[0][0] += a.x*b.x; acc[0][1] += a.x*b.y; acc[0][2] += a.x*b.z; acc[0][3] += a.x*b.w;
      acc[1][0] += a.y*b.x; acc[1][1] += a.y*b.y; acc[1][2] += a.y*b.z; acc[1][3] += a.y*b.w;
      acc[2][0] += a.z*b.x; acc[2][1] += a.z*b.y; acc[2][2] += a.z*b.z; acc[2][3] += a.z*b.w;
      acc[3][0] += a.w*b.x; acc[3][1] += a.w*b.y; acc[3][2] += a.w*b.z; acc[3][3] += a.w*b.w;
    }
    __syncthreads();
  }
  float sqi[4], sqj[4];
#pragma unroll
  for (int ii = 0; ii < 4; ++ii) {
    int i = i0 + 4 * ti + ii; if (i >= SS) i = SS - 1;
    sqi[ii] = sq[n * SS + i];
    int j = j0 + 4 * tj + ii; if (j >= SS) j = SS - 1;
    sqj[ii] = sq[n * SS + j];
  }
  float mx = -3e38f;
  float outv[4][4];
#pragma unroll
  for (int ii = 0; ii < 4; ++ii)
#pragma unroll
    for (int jj = 0; jj < 4; ++jj) {
      float o = sqi[ii] + sqj[jj] - 2.f * acc[ii][jj];
      outv[ii][jj] = o;
      mx = fmaxf(mx, o);
    }
#pragma unroll
  for (int ii = 0; ii < 4; ++ii) {
    int i = i0 + 4 * ti + ii;
    if (i < SS) {
      int jb = j0 + 4 * tj;
      if (jb + 3 < SS) {
        float4 o; o.x = outv[ii][0]; o.y = outv[ii][1]; o.z = outv[ii][2]; o.w = outv[ii][3];
        *(float4*)&d2[(size_t)(n * SS + i) * SS + jb] = o;
      } else {
        for (int jj = 0; jj < 4; ++jj)
          if (jb + jj < SS) d2[(size_t)(n * SS + i) * SS + jb + jj] = outv[ii][jj];
      }
    }
  }
  redm[tid] = mx; __syncthreads();
  for (int s2 = 128; s2 > 0; s2 >>= 1) {
    if (tid < s2) redm[tid] = fmaxf(redm[tid], redm[tid + s2]);
    __syncthreads();
  }
  if (tid == 0) atomicMax(&d2max[n], __float_as_int(redm[0]));
}

// ---------------- K4: KNN density -------------------------------------------
__global__ __launch_bounds__(256) void k_knn(
    const float* __restrict__ d2, float* __restrict__ density)
{
  __shared__ float row[SS];
  __shared__ float swv[4]; __shared__ int swi[4];
  __shared__ float s_sum;
  const int i = blockIdx.x, n = blockIdx.y, tid = threadIdx.x;
  const float* dr = &d2[(size_t)(n * SS + i) * SS];
  for (int e = tid; e < SS; e += 256) row[e] = dr[e];
  if (tid == 0) s_sum = 0.f;
  __syncthreads();
  const int wid = tid >> 6, lane = tid & 63;
  for (int r = 0; r < KNN; ++r) {
    float mv = 3e38f; int mi = 0;
    for (int e = tid; e < SS; e += 256) {
      float v = row[e];
      if (v < mv) { mv = v; mi = e; }
    }
#pragma unroll
    for (int o = 32; o > 0; o >>= 1) {
      float ov = __shfl_down(mv, o); int oi = __shfl_down(mi, o);
      if (ov < mv) { mv = ov; mi = oi; }
    }
    if (lane == 0) { swv[wid] = mv; swi[wid] = mi; }
    __syncthreads();
    if (tid == 0) {
      float bv = swv[0]; int bi = swi[0];
      for (int w = 1; w < 4; ++w) if (swv[w] < bv) { bv = swv[w]; bi = swi[w]; }
      s_sum += fmaxf(bv, 1e-12f);
      row[bi] = 3e38f;
    }
    __syncthreads();
  }
  if (tid == 0) density[n * SS + i] = expf(-s_sum * (1.f / (KNN * CCH)));
}

// ---------------- K5: parent dist + cscore ----------------------------------
__global__ __launch_bounds__(256) void k_parent(
    const float* __restrict__ d2, const float* __restrict__ density,
    const int* __restrict__ d2max, float* __restrict__ cscore)
{
  __shared__ float swv[4];
  const int i = blockIdx.x, n = blockIdx.y, tid = threadIdx.x;
  const float di = density[n * SS + i];
  const float* dr = &d2[(size_t)(n * SS + i) * SS];
  float m = 3e38f;
  for (int e = tid; e < SS; e += 256) {
    float dj = density[n * SS + e];
    float v = dr[e];
    if (dj > di && v < m) m = v;
  }
#pragma unroll
  for (int o = 32; o > 0; o >>= 1) m = fminf(m, __shfl_down(m, o));
  int wid = tid >> 6, lane = tid & 63;
  if (lane == 0) swv[wid] = m;
  __syncthreads();
  if (tid == 0) {
    float mm = fminf(fminf(swv[0], swv[1]), fminf(swv[2], swv[3]));
    mm = fminf(mm, __int_as_float(d2max[n]));
    float pd = sqrtf(fmaxf(mm, 1e-12f)) * 0.0625f;
    cscore[n * SS + i] = pd * di;
  }
}

// ---------------- K6: top-K cluster centers ---------------------------------
__global__ __launch_bounds__(1024) void k_topk_centers(
    const float* __restrict__ cscore, int* __restrict__ index_down)
{
  __shared__ unsigned long long keys[4096];
  const int n = blockIdx.x, tid = threadIdx.x;
  for (int i = tid; i < 4096; i += 1024) {
    unsigned long long kv = 0ULL;
    if (i < SS) kv = ((unsigned long long)fmap(cscore[n * SS + i]) << 32) | (unsigned)(~(unsigned)i);
    keys[i] = kv;
  }
  __syncthreads();
  bitonic4096_desc(keys, tid);
  for (int t = tid; t < KCL; t += 1024)
    index_down[n * KCL + t] = (int)(~(unsigned)keys[t]);
}

// ---------------- K7: cluster assignment ------------------------------------
__global__ __launch_bounds__(256) void k_assign(
    const float* __restrict__ d2, const int* __restrict__ index_down,
    int* __restrict__ idx_cluster)
{
  const int n = blockIdx.y;
  const int i = blockIdx.x * 256 + threadIdx.x;
  if (i >= SS) return;
  float best = 3e38f; int bk = 0;
  for (int k = 0; k < KCL; ++k) {
    int r = index_down[n * KCL + k];
    float v = d2[(size_t)(n * SS + r) * SS + i];
    if (v < best) { best = v; bk = k; }
  }
  idx_cluster[n * SS + i] = bk;
}

__global__ void k_center_overwrite(const int* __restrict__ index_down, int* __restrict__ idx_cluster) {
  const int n = blockIdx.x; const int k = threadIdx.x;
  if (k < KCL) idx_cluster[n * SS + index_down[n * KCL + k]] = k;
}

// ---------------- K8/K9: merge ----------------------------------------------
__global__ __launch_bounds__(256) void k_weights(
    const int* __restrict__ idx_cluster, const float* __restrict__ conf, float* __restrict__ all_w)
{
  const int n = blockIdx.y; const int i = blockIdx.x * 256 + threadIdx.x;
  if (i >= SS) return;
  atomicAdd(&all_w[n * KCL + idx_cluster[n * SS + i]], conf[n * SS + i]);
}

__global__ __launch_bounds__(256) void k_merge(
    const int* __restrict__ idx_cluster, const float* __restrict__ conf,
    const float* __restrict__ all_w, const float* __restrict__ tokens, float* __restrict__ merged)
{
  const int t = blockIdx.x, n = blockIdx.y, c = threadIdx.x;
  const int k = idx_cluster[n * SS + t];
  const float w = conf[n * SS + t] / (all_w[n * KCL + k] + 1e-6f);
  atomicAdd(&merged[(size_t)(n * KCL + k) * CCH + c],
            tokens[(size_t)(n * SS + t) * CCH + c] * w);
}

// ---------------- K10: pixel -> cluster map ---------------------------------
__global__ __launch_bounds__(256) void k_kmap(
    const int* __restrict__ topk_idx, const int* __restrict__ idx_cluster, int* __restrict__ kmap)
{
  const int n = blockIdx.y; const int i = blockIdx.x * 256 + threadIdx.x;
  if (i >= SS) return;
  kmap[n * HWP + topk_idx[n * SS + i]] = idx_cluster[n * SS + i];
}

// ---------------- K11: ego flags --------------------------------------------
__global__ void k_ego(const int* __restrict__ record_len, int R, int* __restrict__ ego) {
  if (threadIdx.x == 0 && blockIdx.x == 0) {
    int acc = 0;
    for (int r = 0; r < R; ++r) {
      if (acc >= 0 && acc < NN) ego[acc] = 1;
      acc += record_len[r];
    }
  }
}

// ---------------- K12: final output -----------------------------------------
__global__ __launch_bounds__(256) void k_output(
    const float* __restrict__ x, const float* __restrict__ merged,
    const int* __restrict__ kmap, const int* __restrict__ ego, float* __restrict__ out)
{
  const int n = blockIdx.z, c = blockIdx.y;
  const int p = blockIdx.x * 256 + threadIdx.x;
  if (p >= HWP) return;
  float v;
  if (ego[n]) {
    v = x[(size_t)(n * CCH + c) * HWP + p];
  } else {
    int k = kmap[n * HWP + p];
    v = (k >= 0) ? merged[(size_t)(n * KCL + k) * CCH + c] : 0.f;
  }
  out[(size_t)(n * CCH + c) * HWP + p] = v;
}

// ---------------- launch -----------------------------------------------------
extern "C" void kernel_launch(void* const* d_in, const int* in_sizes, int n_in,
                              void* d_out, int out_size, void* d_ws, size_t ws_size,
                              hipStream_t stream)
{
  const float* x   = (const float*)d_in[0];
  const float* w1  = (const float*)d_in[1];
  const float* b1  = (const float*)d_in[2];
  const float* w2  = (const float*)d_in[3];
  const float* b2  = (const float*)d_in[4];
  const float* pri = (const float*)d_in[5];
  const int*   rec = (const int*)d_in[6];
  const int R = in_sizes[6];
  float* out = (float*)d_out;

  char* ws = (char*)d_ws;
  size_t off = 0;
  auto alloc = [&](size_t bytes) -> char* {
    char* p = ws + off;
    off = (off + bytes + 255) & ~(size_t)255;
    return p;
  };
  float* scores      = (float*)alloc(sizeof(float) * NN * HWP);
  int*   topk_idx    = (int*)  alloc(sizeof(int)   * NN * SS);
  float* conf        = (float*)alloc(sizeof(float) * NN * SS);
  float* tokens      = (float*)alloc(sizeof(float) * (size_t)NN * SS * CCH);
  float* sq          = (float*)alloc(sizeof(float) * NN * SS);
  float* density     = (float*)alloc(sizeof(float) * NN * SS);
  float* cscore      = (float*)alloc(sizeof(float) * NN * SS);
  int*   d2max       = (int*)  alloc(sizeof(int)   * NN);
  int*   index_down  = (int*)  alloc(sizeof(int)   * NN * KCL);
  int*   idx_cluster = (int*)  alloc(sizeof(int)   * NN * SS);
  float* all_w       = (float*)alloc(sizeof(float) * NN * KCL);
  float* merged      = (float*)alloc(sizeof(float) * (size_t)NN * KCL * CCH);
  int*   kmap        = (int*)  alloc(sizeof(int)   * NN * HWP);
  int*   ego         = (int*)  alloc(sizeof(int)   * NN);
  float* d2          = (float*)alloc(sizeof(float) * (size_t)NN * SS * SS);
  if (off > ws_size)
    fprintf(stderr, "ERMVP kernel: workspace too small: need %zu, have %zu\n", off, ws_size);

  hipMemsetAsync(d2max, 0, sizeof(int) * NN, stream);
  hipMemsetAsync(all_w, 0, sizeof(float) * NN * KCL, stream);
  hipMemsetAsync(merged, 0, sizeof(float) * (size_t)NN * KCL * CCH, stream);
  hipMemsetAsync(kmap, 0xFF, sizeof(int) * NN * HWP, stream);
  hipMemsetAsync(ego, 0, sizeof(int) * NN, stream);

  k_score<<<dim3((HWP + 63) / 64, NN), 256, 0, stream>>>(x, w1, b1, w2, b2, pri, scores);
  k_topk_sample<<<NN, 1024, 0, stream>>>(scores, topk_idx, conf);
  k_gather_ln<<<dim3(SS, NN), 256, 0, stream>>>(x, topk_idx, conf, tokens, sq);
  k_gram<<<dim3((SS + 63) / 64, (SS + 63) / 64, NN), 256, 0, stream>>>(tokens, sq, d2, d2max);
  k_knn<<<dim3(SS, NN), 256, 0, stream>>>(d2, density);
  k_parent<<<dim3(SS, NN), 256, 0, stream>>>(d2, density, d2max, cscore);
  k_topk_centers<<<NN, 1024, 0, stream>>>(cscore, index_down);
  k_assign<<<dim3((SS + 255) / 256, NN), 256, 0, stream>>>(d2, index_down, idx_cluster);
  k_center_overwrite<<<NN, 320, 0, stream>>>(index_down, idx_cluster);
  k_weights<<<dim3((SS + 255) / 256, NN), 256, 0, stream>>>(idx_cluster, conf, all_w);
  k_merge<<<dim3(SS, NN), 256, 0, stream>>>(idx_cluster, conf, all_w, tokens, merged);
  k_kmap<<<dim3((SS + 255) / 256, NN), 256, 0, stream>>>(topk_idx, idx_cluster, kmap);
  k_ego<<<1, 64, 0, stream>>>(rec, R, ego);
  k_output<<<dim3((HWP + 255) / 256, CCH, NN), 256, 0, stream>>>(x, merged, kmap, ego, out);
}

// Round 2
// 1252.807 us; speedup vs baseline: 1.2851x; 1.2851x over previous
//
#include <hip/hip_runtime.h>
#include <cstdio>
#include <cstdint>

#define NN  8
#define CCH 256
#define HWP 25200
#define SS  2520
#define KCL 315
#define KNN 10

__device__ __forceinline__ unsigned fmap(float f) {
  unsigned u = __float_as_uint(f);
  return (u & 0x80000000u) ? ~u : (u | 0x80000000u);
}
__device__ __forceinline__ float funmap(unsigned u) {
  unsigned b = (u & 0x80000000u) ? (u & 0x7fffffffu) : ~u;
  return __uint_as_float(b);
}

// ---------------- K-1: transpose w1 [d][c] -> w1T [c][d] --------------------
__global__ __launch_bounds__(256) void k_w1t(const float* __restrict__ w1, float* __restrict__ w1T) {
  __shared__ float tile[32][33];
  const int bx = blockIdx.x * 32, by = blockIdx.y * 32;
  const int tx = threadIdx.x, ty = threadIdx.y;  // 32 x 8
  for (int r = 0; r < 32; r += 8)
    tile[ty + r][tx] = w1[(by + ty + r) * CCH + bx + tx];
  __syncthreads();
  for (int r = 0; r < 32; r += 8)
    w1T[(bx + ty + r) * CCH + by + tx] = tile[tx][ty + r];
}

// ---------------- K0: score net (64px x 256d tile GEMM) ---------------------
__global__ __launch_bounds__(256) void k_score(
    const float* __restrict__ x, const float* __restrict__ w1T,
    const float* __restrict__ b1, const float* __restrict__ w2,
    const float* __restrict__ b2, const float* __restrict__ pri,
    float* __restrict__ scores)
{
  __shared__ float Wl[16 * 256];   // [kk][d]
  __shared__ float Xl[16 * 64];    // [kk][p]
  __shared__ float red[64 * 33];
  const int n = blockIdx.y, p0 = blockIdx.x * 64, tid = threadIdx.x;
  const int dt = tid & 31, pt = tid >> 5;
  float acc[8][8];
#pragma unroll
  for (int i = 0; i < 8; ++i)
#pragma unroll
    for (int j = 0; j < 8; ++j) acc[i][j] = 0.f;

  for (int c0 = 0; c0 < CCH; c0 += 16) {
    // stage W: flat contiguous copy (no transpose needed)
    {
      const float4* src = (const float4*)(w1T + (size_t)c0 * CCH);
      float4* dst = (float4*)Wl;
#pragma unroll
      for (int i = 0; i < 4; ++i) dst[tid + 256 * i] = src[tid + 256 * i];
    }
    // stage X: [kk][64p]
    {
      int kk = tid >> 4, q = tid & 15;
      int gp = p0 + 4 * q; if (gp > HWP - 4) gp = HWP - 4;
      *(float4*)&Xl[kk * 64 + 4 * q] = *(const float4*)&x[(size_t)(n * CCH + c0 + kk) * HWP + gp];
    }
    __syncthreads();
#pragma unroll
    for (int kk = 0; kk < 16; ++kk) {
      const float4 w0 = *(const float4*)&Wl[kk * 256 + 4 * dt];
      const float4 w1v = *(const float4*)&Wl[kk * 256 + 128 + 4 * dt];
      const float4 x0 = *(const float4*)&Xl[kk * 64 + 4 * pt];
      const float4 x1 = *(const float4*)&Xl[kk * 64 + 32 + 4 * pt];
      const float a[8] = {w0.x, w0.y, w0.z, w0.w, w1v.x, w1v.y, w1v.z, w1v.w};
      const float b[8] = {x0.x, x0.y, x0.z, x0.w, x1.x, x1.y, x1.z, x1.w};
#pragma unroll
      for (int di = 0; di < 8; ++di)
#pragma unroll
        for (int pj = 0; pj < 8; ++pj) acc[di][pj] += a[di] * b[pj];
    }
    __syncthreads();
  }
  // epilogue: relu + dot with w2 over this thread's 8 d's
  float part[8];
#pragma unroll
  for (int pj = 0; pj < 8; ++pj) part[pj] = 0.f;
#pragma unroll
  for (int di = 0; di < 8; ++di) {
    int d = (di < 4) ? (4 * dt + di) : (128 + 4 * dt + di - 4);
    float bb = b1[d], wv = w2[d];
#pragma unroll
    for (int pj = 0; pj < 8; ++pj) {
      float h = acc[di][pj] + bb; h = h > 0.f ? h : 0.f;
      part[pj] += h * wv;
    }
  }
#pragma unroll
  for (int pj = 0; pj < 8; ++pj) {
    int px = (pj < 4) ? (4 * pt + pj) : (32 + 4 * pt + pj - 4);
    red[px * 33 + dt] = part[pj];
  }
  __syncthreads();
  if (tid < 64) {
    float s = b2[0];
#pragma unroll
    for (int g = 0; g < 32; ++g) s += red[tid * 33 + g];
    float sc = 1.f / (1.f + expf(-s));
    int p = p0 + tid;
    if (p < HWP) scores[n * HWP + p] = sc * pri[n * HWP + p];
  }
}

// ---------------- shared bitonic (4096 u64 desc, 1024 thr) ------------------
__device__ __forceinline__ void bitonic4096_desc(unsigned long long* keys, int tid) {
  for (int k = 2; k <= 4096; k <<= 1) {
    for (int j = k >> 1; j > 0; j >>= 1) {
      for (int i = tid; i < 4096; i += 1024) {
        int ixj = i ^ j;
        if (ixj > i) {
          unsigned long long a = keys[i], b = keys[ixj];
          bool up = ((i & k) == 0);
          if ((a < b) == up) { keys[i] = b; keys[ixj] = a; }
        }
      }
      __syncthreads();
    }
  }
}

// ---------------- K1: exact top-S sample (radix select + sort) --------------
__global__ __launch_bounds__(1024) void k_topk_sample(
    const float* __restrict__ scores, int* __restrict__ topk_idx, float* __restrict__ conf)
{
  __shared__ unsigned hist[256];
  __shared__ unsigned long long keys[4096];
  __shared__ unsigned sh_rank, sh_chosen;
  __shared__ int sh_cnt;
  const int n = blockIdx.x;
  const int tid = threadIdx.x;
  if (tid == 0) sh_rank = SS;
  __syncthreads();
  unsigned prefix = 0, pmask = 0;
  for (int shift = 24; shift >= 0; shift -= 8) {
    for (int b = tid; b < 256; b += 1024) hist[b] = 0;
    __syncthreads();
    for (int e = tid; e < HWP; e += 1024) {
      unsigned u = fmap(scores[n * HWP + e]);
      if ((u & pmask) == prefix) atomicAdd(&hist[(u >> shift) & 255u], 1u);
    }
    __syncthreads();
    if (tid == 0) {
      unsigned r = sh_rank, chosen = 0;
      for (int b = 255; b >= 0; --b) {
        unsigned cb = hist[b];
        if (cb < r) r -= cb; else { chosen = (unsigned)b; break; }
      }
      sh_rank = r; sh_chosen = chosen;
    }
    __syncthreads();
    prefix |= sh_chosen << shift;
    pmask  |= 0xFFu << shift;
    __syncthreads();
  }
  const unsigned uT = prefix;
  if (tid == 0) sh_cnt = 0;
  for (int i = tid; i < 4096; i += 1024) keys[i] = 0ULL;
  __syncthreads();
  for (int e = tid; e < HWP; e += 1024) {
    unsigned u = fmap(scores[n * HWP + e]);
    if (u >= uT) {
      int s = atomicAdd(&sh_cnt, 1);
      if (s < 4096) keys[s] = ((unsigned long long)u << 32) | (unsigned)(~(unsigned)e);
    }
  }
  __syncthreads();
  bitonic4096_desc(keys, tid);
  for (int t = tid; t < SS; t += 1024) {
    unsigned long long kv = keys[t];
    topk_idx[n * SS + t] = (int)(~(unsigned)kv);
    conf[n * SS + t] = funmap((unsigned)(kv >> 32));
  }
}

// ---------------- reductions ------------------------------------------------
__device__ __forceinline__ float block_sum256(float v, float* scratch) {
#pragma unroll
  for (int o = 32; o > 0; o >>= 1) v += __shfl_down(v, o);
  int wid = threadIdx.x >> 6, lane = threadIdx.x & 63;
  if (lane == 0) scratch[wid] = v;
  __syncthreads();
  float r = scratch[0] + scratch[1] + scratch[2] + scratch[3];
  __syncthreads();
  return r;
}

// ---------------- K2: gather + layernorm + conf + sq ------------------------
__global__ __launch_bounds__(256) void k_gather_ln(
    const float* __restrict__ x, const int* __restrict__ topk_idx,
    const float* __restrict__ conf, float* __restrict__ tokens, float* __restrict__ sq)
{
  __shared__ float scratch[4];
  const int t = blockIdx.x, n = blockIdx.y, c = threadIdx.x;
  const int p = topk_idx[n * SS + t];
  float v = x[(size_t)(n * CCH + c) * HWP + p];
  float mu = block_sum256(v, scratch) * (1.f / CCH);
  float d = v - mu;
  float var = block_sum256(d * d, scratch) * (1.f / CCH);
  float inv = 1.f / sqrtf(var + 1e-5f);
  float tok = d * inv * conf[n * SS + t];
  tokens[(size_t)(n * SS + t) * CCH + c] = tok;
  float s2 = block_sum256(tok * tok, scratch);
  if (c == 0) sq[n * SS + t] = s2;
}

// ---------------- K2b: transpose tokens [n][t][c] -> tokensT [n][c][t] ------
__global__ __launch_bounds__(256) void k_ttrans(
    const float* __restrict__ tokens, float* __restrict__ tokensT)
{
  __shared__ float tile[64][68];
  const int n = blockIdx.z, t0 = blockIdx.x * 64, cc0 = blockIdx.y * 64;
  const int tid = threadIdx.x;
  for (int l = tid; l < 1024; l += 256) {
    int tr = l >> 4, q = l & 15;
    int gt = t0 + tr;
    float4 v = {0.f, 0.f, 0.f, 0.f};
    if (gt < SS) v = *(const float4*)&tokens[(size_t)(n * SS + gt) * CCH + cc0 + 4 * q];
    *(float4*)&tile[tr][4 * q] = v;
  }
  __syncthreads();
  for (int l = tid; l < 1024; l += 256) {
    int cr = l >> 4, q = l & 15;
    int gt = t0 + 4 * q;
    if (gt <= SS - 4) {
      float4 v;
      v.x = tile[4 * q + 0][cr]; v.y = tile[4 * q + 1][cr];
      v.z = tile[4 * q + 2][cr]; v.w = tile[4 * q + 3][cr];
      *(float4*)&tokensT[(size_t)(n * CCH + cc0 + cr) * SS + gt] = v;
    }
  }
}

// ---------------- K3: gram GEMM -> d2 (symmetric, upper blocks only) --------
__global__ __launch_bounds__(256) void k_gram(
    const float* __restrict__ tokensT, const float* __restrict__ sq,
    float* __restrict__ d2, int* __restrict__ d2max)
{
  const int bi = blockIdx.y, bj = blockIdx.x, n = blockIdx.z;
  if (bj < bi) return;
  __shared__ float Al[16 * 128], Bl[16 * 128];
  __shared__ float redm[256];
  const int i0 = bi * 128, j0 = bj * 128, tid = threadIdx.x;
  const int ti = tid & 15, tj = tid >> 4;
  float acc[8][8];
#pragma unroll
  for (int i = 0; i < 8; ++i)
#pragma unroll
    for (int j = 0; j < 8; ++j) acc[i][j] = 0.f;

  for (int c0 = 0; c0 < CCH; c0 += 16) {
#pragma unroll
    for (int l0 = 0; l0 < 2; ++l0) {
      int l = threadIdx.x + 256 * l0;
      int kk = l >> 5, q = l & 31;
      size_t srow = (size_t)(n * CCH + c0 + kk) * SS;
      float4 z = {0.f, 0.f, 0.f, 0.f};
      int gi = i0 + 4 * q;
      *(float4*)&Al[kk * 128 + 4 * q] = (gi <= SS - 4) ? *(const float4*)&tokensT[srow + gi] : z;
      int gj = j0 + 4 * q;
      *(float4*)&Bl[kk * 128 + 4 * q] = (gj <= SS - 4) ? *(const float4*)&tokensT[srow + gj] : z;
    }
    __syncthreads();
#pragma unroll
    for (int kk = 0; kk < 16; ++kk) {
      const float4 a0 = *(const float4*)&Al[kk * 128 + 4 * ti];
      const float4 a1 = *(const float4*)&Al[kk * 128 + 64 + 4 * ti];
      const float4 b0 = *(const float4*)&Bl[kk * 128 + 4 * tj];
      const float4 b1 = *(const float4*)&Bl[kk * 128 + 64 + 4 * tj];
      const float a[8] = {a0.x, a0.y, a0.z, a0.w, a1.x, a1.y, a1.z, a1.w};
      const float b[8] = {b0.x, b0.y, b0.z, b0.w, b1.x, b1.y, b1.z, b1.w};
#pragma unroll
      for (int ii = 0; ii < 8; ++ii)
#pragma unroll
        for (int jj = 0; jj < 8; ++jj) acc[ii][jj] += a[ii] * b[jj];
    }
    __syncthreads();
  }
  int gi[8], gj[8];
  float sqi[8], sqj[8];
#pragma unroll
  for (int ii = 0; ii < 8; ++ii) {
    gi[ii] = i0 + ((ii < 4) ? (4 * ti + ii) : (64 + 4 * ti + ii - 4));
    sqi[ii] = (gi[ii] < SS) ? sq[n * SS + gi[ii]] : 0.f;
    gj[ii] = j0 + ((ii < 4) ? (4 * tj + ii) : (64 + 4 * tj + ii - 4));
    sqj[ii] = (gj[ii] < SS) ? sq[n * SS + gj[ii]] : 0.f;
  }
  float outv[8][8];
  float mx = -3e38f;
#pragma unroll
  for (int ii = 0; ii < 8; ++ii)
#pragma unroll
    for (int jj = 0; jj < 8; ++jj) {
      float o = sqi[ii] + sqj[jj] - 2.f * acc[ii][jj];
      outv[ii][jj] = o;
      if (gi[ii] < SS && gj[jj] < SS) mx = fmaxf(mx, o);
    }
  // direct stores: rows gi, cols j-groups (contiguous float4s)
#pragma unroll
  for (int ii = 0; ii < 8; ++ii) {
    if (gi[ii] < SS) {
      size_t row = (size_t)(n * SS + gi[ii]) * SS;
      int jb0 = j0 + 4 * tj;
      float4 o0 = {outv[ii][0], outv[ii][1], outv[ii][2], outv[ii][3]};
      *(float4*)&d2[row + jb0] = o0;
      int jb1 = j0 + 64 + 4 * tj;
      if (jb1 < SS) {
        float4 o1 = {outv[ii][4], outv[ii][5], outv[ii][6], outv[ii][7]};
        *(float4*)&d2[row + jb1] = o1;
      }
    }
  }
  // mirror stores for off-diagonal blocks
  if (bi != bj) {
#pragma unroll
    for (int jj = 0; jj < 8; ++jj) {
      if (gj[jj] < SS) {
        size_t row = (size_t)(n * SS + gj[jj]) * SS;
        int ib0 = i0 + 4 * ti;
        float4 m0 = {outv[0][jj], outv[1][jj], outv[2][jj], outv[3][jj]};
        *(float4*)&d2[row + ib0] = m0;
        int ib1 = i0 + 64 + 4 * ti;
        if (ib1 < SS) {
          float4 m1 = {outv[4][jj], outv[5][jj], outv[6][jj], outv[7][jj]};
          *(float4*)&d2[row + ib1] = m1;
        }
      }
    }
  }
  redm[tid] = mx; __syncthreads();
  for (int s = 128; s > 0; s >>= 1) {
    if (tid < s) redm[tid] = fmaxf(redm[tid], redm[tid + s]);
    __syncthreads();
  }
  if (tid == 0) atomicMax(&d2max[n], __float_as_int(redm[0]));
}

// ---------------- K4: KNN density (wave per row, register top-10) -----------
__global__ __launch_bounds__(256) void k_knn(
    const float* __restrict__ d2, float* __restrict__ density)
{
  const int n = blockIdx.y;
  const int w = threadIdx.x >> 6, lane = threadIdx.x & 63;
  const int i = blockIdx.x * 4 + w;
  const float* dr = &d2[(size_t)(n * SS + i) * SS];
  float s[KNN];
#pragma unroll
  for (int k = 0; k < KNN; ++k) s[k] = 3e38f;
  for (int e = lane; e < SS; e += 64) {
    float t = dr[e];
#pragma unroll
    for (int k = 0; k < KNN; ++k) {
      float lo = fminf(s[k], t);
      t = fmaxf(s[k], t);
      s[k] = lo;
    }
  }
  float sum = 0.f;
  for (int r = 0; r < KNN; ++r) {
    float m = s[0];
#pragma unroll
    for (int o = 32; o > 0; o >>= 1) m = fminf(m, __shfl_xor(m, o));
    unsigned long long msk = __ballot(s[0] == m);
    int first = __ffsll(msk) - 1;
    if (lane == first) {
#pragma unroll
      for (int k = 0; k < KNN - 1; ++k) s[k] = s[k + 1];
      s[KNN - 1] = 3e38f;
    }
    sum += fmaxf(m, 1e-12f);
  }
  if (lane == 0) density[n * SS + i] = expf(-sum * (1.f / (KNN * CCH)));
}

// ---------------- K5: parent dist + cscore ----------------------------------
__global__ __launch_bounds__(256) void k_parent(
    const float* __restrict__ d2, const float* __restrict__ density,
    const int* __restrict__ d2max, float* __restrict__ cscore)
{
  __shared__ float swv[4];
  const int i = blockIdx.x, n = blockIdx.y, tid = threadIdx.x;
  const float di = density[n * SS + i];
  const float* dr = &d2[(size_t)(n * SS + i) * SS];
  float m = 3e38f;
  for (int e = tid; e < SS; e += 256) {
    float dj = density[n * SS + e];
    float v = dr[e];
    if (dj > di && v < m) m = v;
  }
#pragma unroll
  for (int o = 32; o > 0; o >>= 1) m = fminf(m, __shfl_down(m, o));
  int wid = tid >> 6, lane = tid & 63;
  if (lane == 0) swv[wid] = m;
  __syncthreads();
  if (tid == 0) {
    float mm = fminf(fminf(swv[0], swv[1]), fminf(swv[2], swv[3]));
    mm = fminf(mm, __int_as_float(d2max[n]));
    float pd = sqrtf(fmaxf(mm, 1e-12f)) * 0.0625f;
    cscore[n * SS + i] = pd * di;
  }
}

// ---------------- K6: top-K cluster centers ---------------------------------
__global__ __launch_bounds__(1024) void k_topk_centers(
    const float* __restrict__ cscore, int* __restrict__ index_down)
{
  __shared__ unsigned long long keys[4096];
  const int n = blockIdx.x, tid = threadIdx.x;
  for (int i = tid; i < 4096; i += 1024) {
    unsigned long long kv = 0ULL;
    if (i < SS) kv = ((unsigned long long)fmap(cscore[n * SS + i]) << 32) | (unsigned)(~(unsigned)i);
    keys[i] = kv;
  }
  __syncthreads();
  bitonic4096_desc(keys, tid);
  for (int t = tid; t < KCL; t += 1024)
    index_down[n * KCL + t] = (int)(~(unsigned)keys[t]);
}

// ---------------- K7: cluster assignment ------------------------------------
__global__ __launch_bounds__(256) void k_assign(
    const float* __restrict__ d2, const int* __restrict__ index_down,
    int* __restrict__ idx_cluster)
{
  const int n = blockIdx.y;
  const int i = blockIdx.x * 256 + threadIdx.x;
  if (i >= SS) return;
  float best = 3e38f; int bk = 0;
  for (int k = 0; k < KCL; ++k) {
    int r = index_down[n * KCL + k];
    float v = d2[(size_t)(n * SS + r) * SS + i];
    if (v < best) { best = v; bk = k; }
  }
  idx_cluster[n * SS + i] = bk;
}

__global__ void k_center_overwrite(const int* __restrict__ index_down, int* __restrict__ idx_cluster) {
  const int n = blockIdx.x; const int k = threadIdx.x;
  if (k < KCL) idx_cluster[n * SS + index_down[n * KCL + k]] = k;
}

// ---------------- K8/K9: merge ----------------------------------------------
__global__ __launch_bounds__(256) void k_weights(
    const int* __restrict__ idx_cluster, const float* __restrict__ conf, float* __restrict__ all_w)
{
  const int n = blockIdx.y; const int i = blockIdx.x * 256 + threadIdx.x;
  if (i >= SS) return;
  atomicAdd(&all_w[n * KCL + idx_cluster[n * SS + i]], conf[n * SS + i]);
}

__global__ __launch_bounds__(256) void k_merge(
    const int* __restrict__ idx_cluster, const float* __restrict__ conf,
    const float* __restrict__ all_w, const float* __restrict__ tokens, float* __restrict__ merged)
{
  const int t = blockIdx.x, n = blockIdx.y, c = threadIdx.x;
  const int k = idx_cluster[n * SS + t];
  const float w = conf[n * SS + t] / (all_w[n * KCL + k] + 1e-6f);
  atomicAdd(&merged[(size_t)(n * KCL + k) * CCH + c],
            tokens[(size_t)(n * SS + t) * CCH + c] * w);
}

// ---------------- K10: pixel -> cluster map ---------------------------------
__global__ __launch_bounds__(256) void k_kmap(
    const int* __restrict__ topk_idx, const int* __restrict__ idx_cluster, int* __restrict__ kmap)
{
  const int n = blockIdx.y; const int i = blockIdx.x * 256 + threadIdx.x;
  if (i >= SS) return;
  kmap[n * HWP + topk_idx[n * SS + i]] = idx_cluster[n * SS + i];
}

// ---------------- K11: ego flags --------------------------------------------
__global__ void k_ego(const int* __restrict__ record_len, int R, int* __restrict__ ego) {
  if (threadIdx.x == 0 && blockIdx.x == 0) {
    int acc = 0;
    for (int r = 0; r < R; ++r) {
      if (acc >= 0 && acc < NN) ego[acc] = 1;
      acc += record_len[r];
    }
  }
}

// ---------------- K12: final output (float4) --------------------------------
__global__ __launch_bounds__(256) void k_output(
    const float* __restrict__ x, const float* __restrict__ merged,
    const int* __restrict__ kmap, const int* __restrict__ ego, float* __restrict__ out)
{
  const int n = blockIdx.z, c = blockIdx.y;
  const int p4 = blockIdx.x * 256 + threadIdx.x;
  if (p4 >= HWP / 4) return;
  const size_t base = (size_t)(n * CCH + c) * HWP + 4 * p4;
  float4 v;
  if (ego[n]) {
    v = *(const float4*)&x[base];
  } else {
    int4 k4 = *(const int4*)&kmap[n * HWP + 4 * p4];
    const float* mb = &merged[(size_t)n * KCL * CCH + c];
    v.x = (k4.x >= 0) ? mb[(size_t)k4.x * CCH] : 0.f;
    v.y = (k4.y >= 0) ? mb[(size_t)k4.y * CCH] : 0.f;
    v.z = (k4.z >= 0) ? mb[(size_t)k4.z * CCH] : 0.f;
    v.w = (k4.w >= 0) ? mb[(size_t)k4.w * CCH] : 0.f;
  }
  *(float4*)&out[base] = v;
}

// ---------------- launch -----------------------------------------------------
extern "C" void kernel_launch(void* const* d_in, const int* in_sizes, int n_in,
                              void* d_out, int out_size, void* d_ws, size_t ws_size,
                              hipStream_t stream)
{
  const float* x   = (const float*)d_in[0];
  const float* w1  = (const float*)d_in[1];
  const float* b1  = (const float*)d_in[2];
  const float* w2  = (const float*)d_in[3];
  const float* b2  = (const float*)d_in[4];
  const float* pri = (const float*)d_in[5];
  const int*   rec = (const int*)d_in[6];
  const int R = in_sizes[6];
  float* out = (float*)d_out;

  char* ws = (char*)d_ws;
  size_t off = 0;
  auto alloc = [&](size_t bytes) -> char* {
    char* p = ws + off;
    off = (off + bytes + 255) & ~(size_t)255;
    return p;
  };
  float* scores      = (float*)alloc(sizeof(float) * NN * HWP);
  int*   topk_idx    = (int*)  alloc(sizeof(int)   * NN * SS);
  float* conf        = (float*)alloc(sizeof(float) * NN * SS);
  float* tokens      = (float*)alloc(sizeof(float) * (size_t)NN * SS * CCH);
  float* tokensT     = (float*)alloc(sizeof(float) * (size_t)NN * CCH * SS);
  float* w1T         = (float*)alloc(sizeof(float) * CCH * CCH);
  float* sq          = (float*)alloc(sizeof(float) * NN * SS);
  float* density     = (float*)alloc(sizeof(float) * NN * SS);
  float* cscore      = (float*)alloc(sizeof(float) * NN * SS);
  int*   d2max       = (int*)  alloc(sizeof(int)   * NN);
  int*   index_down  = (int*)  alloc(sizeof(int)   * NN * KCL);
  int*   idx_cluster = (int*)  alloc(sizeof(int)   * NN * SS);
  float* all_w       = (float*)alloc(sizeof(float) * NN * KCL);
  float* merged      = (float*)alloc(sizeof(float) * (size_t)NN * KCL * CCH);
  int*   kmap        = (int*)  alloc(sizeof(int)   * NN * HWP);
  int*   ego         = (int*)  alloc(sizeof(int)   * NN);
  float* d2          = (float*)alloc(sizeof(float) * (size_t)NN * SS * SS);
  if (off > ws_size)
    fprintf(stderr, "ERMVP kernel: workspace too small: need %zu, have %zu\n", off, ws_size);

  hipMemsetAsync(d2max, 0, sizeof(int) * NN, stream);
  hipMemsetAsync(all_w, 0, sizeof(float) * NN * KCL, stream);
  hipMemsetAsync(merged, 0, sizeof(float) * (size_t)NN * KCL * CCH, stream);
  hipMemsetAsync(kmap, 0xFF, sizeof(int) * NN * HWP, stream);
  hipMemsetAsync(ego, 0, sizeof(int) * NN, stream);

  k_w1t<<<dim3(8, 8), dim3(32, 8), 0, stream>>>(w1, w1T);
  k_score<<<dim3((HWP + 63) / 64, NN), 256, 0, stream>>>(x, w1T, b1, w2, b2, pri, scores);
  k_topk_sample<<<NN, 1024, 0, stream>>>(scores, topk_idx, conf);
  k_gather_ln<<<dim3(SS, NN), 256, 0, stream>>>(x, topk_idx, conf, tokens, sq);
  k_ttrans<<<dim3((SS + 63) / 64, CCH / 64, NN), 256, 0, stream>>>(tokens, tokensT);
  k_gram<<<dim3(20, 20, NN), 256, 0, stream>>>(tokensT, sq, d2, d2max);
  k_knn<<<dim3(SS / 4, NN), 256, 0, stream>>>(d2, density);
  k_parent<<<dim3(SS, NN), 256, 0, stream>>>(d2, density, d2max, cscore);
  k_topk_centers<<<NN, 1024, 0, stream>>>(cscore, index_down);
  k_assign<<<dim3((SS + 255) / 256, NN), 256, 0, stream>>>(d2, index_down, idx_cluster);
  k_center_overwrite<<<NN, 320, 0, stream>>>(index_down, idx_cluster);
  k_weights<<<dim3((SS + 255) / 256, NN), 256, 0, stream>>>(idx_cluster, conf, all_w);
  k_merge<<<dim3(SS, NN), 256, 0, stream>>>(idx_cluster, conf, all_w, tokens, merged);
  k_kmap<<<dim3((SS + 255) / 256, NN), 256, 0, stream>>>(topk_idx, idx_cluster, kmap);
  k_ego<<<1, 64, 0, stream>>>(rec, R, ego);
  k_output<<<dim3((HWP / 4 + 255) / 256, CCH, NN), 256, 0, stream>>>(x, merged, kmap, ego, out);
}